// Round 23
// baseline (495.782 us; speedup 1.0000x reference)
//
#include <hip/hip_runtime.h>
#include <cstdint>
#include <cstddef>

// DecoderLayer: B=4, L=S=1024, D=1024, H=16, dh=64, DFF=4096
// Outputs: x [4,1024,1024] f32, self_w [4,1024,1024] f32, cross_w [4,1024,1024] f32

#define DEVI __device__ __forceinline__

typedef unsigned short u16;
typedef unsigned int u32;
typedef float f32x4 __attribute__((ext_vector_type(4)));
typedef short bf16x8 __attribute__((ext_vector_type(8)));

DEVI float bf2f(u16 u) { union { u32 i; float f; } x; x.i = ((u32)u) << 16; return x.f; }
DEVI u16 f2bf(float f) {
  union { float f; u32 i; } x; x.f = f;
  u32 r = x.i + 0x7fffu + ((x.i >> 16) & 1u);
  return (u16)(r >> 16);
}
DEVI u32 cvtpk(float lo, float hi) {  // bf16x2 pack, RTNE
  u32 r;
  asm("v_cvt_pk_bf16_f32 %0, %1, %2" : "=v"(r) : "v"(lo), "v"(hi));
  return r;
}
DEVI float unplo(u32 u) { union { u32 i; float f; } x; x.i = u << 16; return x.f; }
DEVI float unphi(u32 u) { union { u32 i; float f; } x; x.i = u & 0xffff0000u; return x.f; }

typedef const __attribute__((address_space(1))) void GV;
typedef __attribute__((address_space(3))) void LV;
DEVI void glds16(const void* g, void* l) {
  __builtin_amdgcn_global_load_lds((GV*)g, (LV*)l, 16, 0, 0);
}

// ---------------- batched f32 -> bf16 convert (7 tensors, one launch) ----------------
struct ConvBatch {
  const float* src[7];
  u16* dst[7];
  int n[7];
};

__global__ __launch_bounds__(256) void conv_batch(ConvBatch cb) {
  int t = blockIdx.y;
  const float* __restrict__ in = cb.src[t];
  u16* __restrict__ out = cb.dst[t];
  int n = cb.n[t];
  int i = (blockIdx.x * 256 + threadIdx.x) * 4;
  int stride = gridDim.x * 256 * 4;
  for (; i < n; i += stride) {
    float4 v = *(const float4*)(in + i);
    ushort4 o; o.x = f2bf(v.x); o.y = f2bf(v.y); o.z = f2bf(v.z); o.w = f2bf(v.w);
    *(ushort4*)(out + i) = o;
  }
}

// ---------------- LayerNorm over D=1024, writes f32 + bf16 ----------------
__global__ __launch_bounds__(256) void ln_kernel(const float* __restrict__ in,
                                                 const float* __restrict__ gw,
                                                 const float* __restrict__ gb,
                                                 float* __restrict__ o32,
                                                 u16* __restrict__ o16) {
  int row = blockIdx.x;
  int t = threadIdx.x;
  const float* p = in + ((size_t)row << 10);
  float4 v = *(const float4*)(p + t * 4);
  float s = v.x + v.y + v.z + v.w;
  float q = v.x * v.x + v.y * v.y + v.z * v.z + v.w * v.w;
#pragma unroll
  for (int off = 32; off; off >>= 1) { s += __shfl_xor(s, off, 64); q += __shfl_xor(q, off, 64); }
  __shared__ float sb[8];
  int lane = t & 63, wv = t >> 6;
  if (!lane) { sb[wv] = s; sb[4 + wv] = q; }
  __syncthreads();
  s = sb[0] + sb[1] + sb[2] + sb[3];
  q = sb[4] + sb[5] + sb[6] + sb[7];
  float mean = s * (1.f / 1024.f);
  float var = q * (1.f / 1024.f) - mean * mean;
  float rs = rsqrtf(var + 1e-5f);
  float4 w4 = *(const float4*)(gw + t * 4);
  float4 b4 = *(const float4*)(gb + t * 4);
  float y0 = (v.x - mean) * rs * w4.x + b4.x;
  float y1 = (v.y - mean) * rs * w4.y + b4.y;
  float y2 = (v.z - mean) * rs * w4.z + b4.z;
  float y3 = (v.w - mean) * rs * w4.w + b4.w;
  float4 o; o.x = y0; o.y = y1; o.z = y2; o.w = y3;
  *(float4*)(o32 + ((size_t)row << 10) + t * 4) = o;
  ushort4 ob; ob.x = f2bf(y0); ob.y = f2bf(y1); ob.z = f2bf(y2); ob.w = f2bf(y3);
  *(ushort4*)(o16 + ((size_t)row << 10) + t * 4) = ob;
}

// ---------------- transpose V: qkv[(b*1024+s)*3072 + col] -> vT[(bh*64+d)*1024 + s]
__global__ __launch_bounds__(256) void transpose_v(const u16* __restrict__ src, u16* __restrict__ dst) {
  __shared__ u16 tile[64][72];
  int bh = blockIdx.y;
  int b = bh >> 4, h = bh & 15;
  int s0 = blockIdx.x * 64;
  int t = threadIdx.x;
#pragma unroll
  for (int p = 0; p < 4; ++p) {
    int s = p * 16 + (t >> 4);
    int d = (t & 15) * 4;
    ushort4 v = *(const ushort4*)(src + ((size_t)(b * 1024 + s0 + s)) * 3072 + h * 64 + d);
    tile[s][d] = v.x; tile[s][d + 1] = v.y; tile[s][d + 2] = v.z; tile[s][d + 3] = v.w;
  }
  __syncthreads();
#pragma unroll
  for (int p = 0; p < 4; ++p) {
    int d = p * 16 + (t >> 4);
    int s = (t & 15) * 4;
    ushort4 v;
    v.x = tile[s][d]; v.y = tile[s + 1][d]; v.z = tile[s + 2][d]; v.w = tile[s + 3][d];
    *(ushort4*)(dst + ((size_t)(bh * 64 + d)) * 1024 + s0 + s) = v;
  }
}

// ---------------- register-resident fused attention, coalesced P store ----------------
// launch_bounds(256,3): matches the real ~3 waves/SIMD reg occupancy; the (256,4)
// bound forced a <=128-reg target the allocator honored with recycling copies.
__global__ __launch_bounds__(256, 3) void attn_fused2(const u16* __restrict__ qkv,
                                                      const u16* __restrict__ vT,
                                                      u16* __restrict__ probs,
                                                      u16* __restrict__ attnv) {
  __shared__ __align__(16) char LdsRaw[32768];  // K halves | P tile [16][1024]u16 | Ored
  __shared__ float wredm[4][2][16];
  __shared__ float wreds[4][2][16];
  float* Ored = (float*)LdsRaw;

  const int hbid = blockIdx.y * 32 + blockIdx.x;          // hw linear id (x fastest)
  const int lbid = (hbid & 7) * 256 + (hbid >> 3);        // XCD-chunked logical id
  const int z = lbid >> 5, b = z >> 4, h = z & 15;
  const int l0 = (lbid & 31) * 32;
  const int tid = threadIdx.x, lane = tid & 63, w = tid >> 6;
  const int fr = lane & 15, c16 = lane >> 4;

  bf16x8 qf[2][2];
#pragma unroll
  for (int i = 0; i < 2; ++i)
#pragma unroll
    for (int kk = 0; kk < 2; ++kk)
      qf[i][kk] = *(const bf16x8*)(qkv + (size_t)(b * 1024 + l0 + 16 * i + fr) * 3072 +
                                   h * 64 + kk * 32 + c16 * 8);

  const u16* Kbase = qkv + (size_t)b * 1024 * 3072 + 1024 + h * 64;

  u32 pk[2][16][2];      // packed bf16 RAW scores (scale folded into exp)
  float mx0 = -1e30f, mx1 = -1e30f;

#pragma unroll
  for (int it = 0; it < 4; ++it) {
    int n = it * 256 + tid;
    int kk = n >> 9, r = (n >> 2) & 127, un = n & 3;
    int su = un ^ ((r >> 1) & 3);
    glds16(Kbase + (size_t)r * 3072 + kk * 32 + su * 8, LdsRaw + n * 16);
  }
  __syncthreads();

#pragma unroll
  for (int cc = 0; cc < 8; ++cc) {
    char* cur = LdsRaw + (cc & 1) * 16384;
    if (cc < 7) {
      char* nxt = LdsRaw + ((cc + 1) & 1) * 16384;
#pragma unroll
      for (int it = 0; it < 4; ++it) {
        int n = it * 256 + tid;
        int kk = n >> 9, r = (n >> 2) & 127, un = n & 3;
        int su = un ^ ((r >> 1) & 3);
        glds16(Kbase + (size_t)((cc + 1) * 128 + r) * 3072 + kk * 32 + su * 8, nxt + n * 16);
      }
    }

    f32x4 acc[2][2];
#pragma unroll
    for (int i = 0; i < 2; ++i)
#pragma unroll
      for (int sj = 0; sj < 2; ++sj) acc[i][sj] = (f32x4){0.f, 0.f, 0.f, 0.f};
    __builtin_amdgcn_s_setprio(1);
#pragma unroll
    for (int kk = 0; kk < 2; ++kk) {
      bf16x8 kf[2];
#pragma unroll
      for (int sj = 0; sj < 2; ++sj) {
        int R = w * 32 + sj * 16 + fr;
        kf[sj] = *(const bf16x8*)(cur + kk * 8192 + R * 64 + ((c16 ^ ((R >> 1) & 3)) << 4));
      }
#pragma unroll
      for (int i = 0; i < 2; ++i)
#pragma unroll
        for (int sj = 0; sj < 2; ++sj)
          acc[i][sj] = __builtin_amdgcn_mfma_f32_16x16x32_bf16(kf[sj], qf[i][kk], acc[i][sj], 0, 0, 0);
    }
    __builtin_amdgcn_s_setprio(0);

    // pack RAW scores, track raw max (scale applied later inside exp)
#pragma unroll
    for (int sj = 0; sj < 2; ++sj) {
      f32x4 a0 = acc[0][sj], a1 = acc[1][sj];
      mx0 = fmaxf(mx0, fmaxf(fmaxf(a0[0], a0[1]), fmaxf(a0[2], a0[3])));
      mx1 = fmaxf(mx1, fmaxf(fmaxf(a1[0], a1[1]), fmaxf(a1[2], a1[3])));
      pk[0][cc * 2 + sj][0] = cvtpk(a0[0], a0[1]); pk[0][cc * 2 + sj][1] = cvtpk(a0[2], a0[3]);
      pk[1][cc * 2 + sj][0] = cvtpk(a1[0], a1[1]); pk[1][cc * 2 + sj][1] = cvtpk(a1[2], a1[3]);
    }
    __syncthreads();
  }

  mx0 = fmaxf(mx0, __shfl_xor(mx0, 16, 64)); mx0 = fmaxf(mx0, __shfl_xor(mx0, 32, 64));
  mx1 = fmaxf(mx1, __shfl_xor(mx1, 16, 64)); mx1 = fmaxf(mx1, __shfl_xor(mx1, 32, 64));
  if (lane < 16) { wredm[w][0][fr] = mx0; wredm[w][1][fr] = mx1; }
  __syncthreads();
  float m0 = fmaxf(fmaxf(wredm[0][0][fr], wredm[1][0][fr]), fmaxf(wredm[2][0][fr], wredm[3][0][fr]));
  float m1 = fmaxf(fmaxf(wredm[0][1][fr], wredm[1][1][fr]), fmaxf(wredm[2][1][fr], wredm[3][1][fr]));

  const float SC = 0.18033688011112042f;   // 0.125 * log2(e)
  float mL0 = m0 * SC, mL1 = m1 * SC;
  float sm0 = 0.f, sm1 = 0.f;
#pragma unroll
  for (int idx = 0; idx < 16; ++idx) {
    u32 a0 = pk[0][idx][0], a1 = pk[0][idx][1];
    float p0 = exp2f(fmaf(unplo(a0), SC, -mL0));
    float p1 = exp2f(fmaf(unphi(a0), SC, -mL0));
    float p2 = exp2f(fmaf(unplo(a1), SC, -mL0));
    float p3 = exp2f(fmaf(unphi(a1), SC, -mL0));
    sm0 += (p0 + p1) + (p2 + p3);
    pk[0][idx][0] = cvtpk(p0, p1); pk[0][idx][1] = cvtpk(p2, p3);
    u32 b0 = pk[1][idx][0], b1 = pk[1][idx][1];
    float q0 = exp2f(fmaf(unplo(b0), SC, -mL1));
    float q1 = exp2f(fmaf(unphi(b0), SC, -mL1));
    float q2 = exp2f(fmaf(unplo(b1), SC, -mL1));
    float q3 = exp2f(fmaf(unphi(b1), SC, -mL1));
    sm1 += (q0 + q1) + (q2 + q3);
    pk[1][idx][0] = cvtpk(q0, q1); pk[1][idx][1] = cvtpk(q2, q3);
  }
  sm0 += __shfl_xor(sm0, 16, 64); sm0 += __shfl_xor(sm0, 32, 64);
  sm1 += __shfl_xor(sm1, 16, 64); sm1 += __shfl_xor(sm1, 32, 64);
  if (lane < 16) { wreds[w][0][fr] = sm0; wreds[w][1][fr] = sm1; }
  __syncthreads();
  float inv0 = 1.f / (wreds[0][0][fr] + wreds[1][0][fr] + wreds[2][0][fr] + wreds[3][0][fr]);
  float inv1 = 1.f / (wreds[0][1][fr] + wreds[1][1][fr] + wreds[2][1][fr] + wreds[3][1][fr]);

#pragma unroll
  for (int i = 0; i < 2; ++i) {
    float inv = i ? inv1 : inv0;
#pragma unroll
    for (int cc = 0; cc < 8; ++cc)
#pragma unroll
      for (int sj = 0; sj < 2; ++sj) {
        int idx = cc * 2 + sj;
        u32 a0 = pk[i][idx][0], a1 = pk[i][idx][1];
        u32 n0 = cvtpk(unplo(a0) * inv, unphi(a0) * inv);
        u32 n1 = cvtpk(unplo(a1) * inv, unphi(a1) * inv);
        pk[i][idx][0] = n0; pk[i][idx][1] = n1;
        int u = cc * 32 + w * 8 + sj * 4 + c16;
        int phys = u ^ (fr & 14);
        uint2 st; st.x = n0; st.y = n1;
        *(uint2*)(LdsRaw + fr * 2048 + phys * 8) = st;
      }
    __syncthreads();
    {
      int r = tid >> 4, pb = tid & 15;
      u16* pg = probs + ((size_t)z << 20) + ((size_t)(l0 + 16 * i + r) << 10);
      int sw = (r & 14) << 3;
#pragma unroll
      for (int j = 0; j < 8; ++j) {
        int p = pb + j * 16;
        bf16x8 v = *(const bf16x8*)(LdsRaw + r * 2048 + ((p * 16) ^ sw));
        *(bf16x8*)(pg + p * 8) = v;
      }
    }
    __syncthreads();
  }

  f32x4 pacc[2][4];
#pragma unroll
  for (int i = 0; i < 2; ++i)
#pragma unroll
    for (int dj = 0; dj < 4; ++dj) pacc[i][dj] = (f32x4){0.f, 0.f, 0.f, 0.f};

  const u16* Vb = vT + ((size_t)z << 16);
  const int laneA = fr + ((c16 & 1) << 5);
  const int laneB = laneA + 16;
  const bool selhi = (c16 & 2) != 0;

#pragma unroll
  for (int cc = 0; cc < 8; ++cc) {
    const int sb = cc * 128 + w * 32;
    const int pidx = cc * 2;
    bf16x8 vf[4];
#pragma unroll
    for (int dj = 0; dj < 4; ++dj)
      vf[dj] = *(const bf16x8*)(Vb + (size_t)(16 * dj + fr) * 1024 + sb + c16 * 8);
#pragma unroll
    for (int i = 0; i < 2; ++i) {
      u32 sA0 = __shfl(pk[i][pidx][0], laneA, 64), sA1 = __shfl(pk[i][pidx][1], laneA, 64);
      u32 sA2 = __shfl(pk[i][pidx + 1][0], laneA, 64), sA3 = __shfl(pk[i][pidx + 1][1], laneA, 64);
      u32 sB0 = __shfl(pk[i][pidx][0], laneB, 64), sB1 = __shfl(pk[i][pidx][1], laneB, 64);
      u32 sB2 = __shfl(pk[i][pidx + 1][0], laneB, 64), sB3 = __shfl(pk[i][pidx + 1][1], laneB, 64);
      union { u32 u[4]; bf16x8 v; } A;
      A.u[0] = selhi ? sA2 : sA0;
      A.u[1] = selhi ? sA3 : sA1;
      A.u[2] = selhi ? sB2 : sB0;
      A.u[3] = selhi ? sB3 : sB1;
      __builtin_amdgcn_s_setprio(1);
#pragma unroll
      for (int dj = 0; dj < 4; ++dj)
        pacc[i][dj] = __builtin_amdgcn_mfma_f32_16x16x32_bf16(A.v, vf[dj], pacc[i][dj], 0, 0, 0);
      __builtin_amdgcn_s_setprio(0);
    }
  }

  if (w < 2) {
    float* Ow = Ored + w * (32 * 68);
#pragma unroll
    for (int i = 0; i < 2; ++i)
#pragma unroll
      for (int dj = 0; dj < 4; ++dj)
#pragma unroll
        for (int q = 0; q < 4; ++q)
          Ow[(16 * i + 4 * c16 + q) * 68 + 16 * dj + fr] = pacc[i][dj][q];
  }
  __syncthreads();
  if (w >= 2) {
    float* Ow = Ored + (w - 2) * (32 * 68);
#pragma unroll
    for (int i = 0; i < 2; ++i)
#pragma unroll
      for (int dj = 0; dj < 4; ++dj)
#pragma unroll
        for (int q = 0; q < 4; ++q)
          Ow[(16 * i + 4 * c16 + q) * 68 + 16 * dj + fr] += pacc[i][dj][q];
  }
  __syncthreads();

  {
    int l = tid >> 3, d0 = (tid & 7) * 8;
    float o[8];
#pragma unroll
    for (int e = 0; e < 8; ++e)
      o[e] = Ored[l * 68 + d0 + e] + Ored[32 * 68 + l * 68 + d0 + e];
    union { u32 u[4]; bf16x8 v; } O;
    O.u[0] = cvtpk(o[0], o[1]); O.u[1] = cvtpk(o[2], o[3]);
    O.u[2] = cvtpk(o[4], o[5]); O.u[3] = cvtpk(o[6], o[7]);
    *(bf16x8*)(attnv + ((size_t)b << 20) + (size_t)(l0 + l) * 1024 + h * 64 + d0) = O.v;
  }
}

// ---------------- mean over 16 heads (16B loads, 2 rows/block) ----------------
__global__ __launch_bounds__(256) void mean_heads(const u16* __restrict__ probs, float* __restrict__ out) {
  int r = blockIdx.x * 2 + (threadIdx.x >> 7);
  int b = r >> 10, l = r & 1023;
  int t = threadIdx.x & 127;
  float a[8];
#pragma unroll
  for (int e = 0; e < 8; ++e) a[e] = 0.f;
  const u16* base = probs + ((size_t)b << 24) + ((size_t)l << 10) + t * 8;
#pragma unroll
  for (int h = 0; h < 16; ++h) {
    bf16x8 v = *(const bf16x8*)(base + ((size_t)h << 20));
#pragma unroll
    for (int e = 0; e < 8; ++e) a[e] += bf2f((u16)v[e]);
  }
  float4 o0, o1;
  o0.x = a[0] * 0.0625f; o0.y = a[1] * 0.0625f; o0.z = a[2] * 0.0625f; o0.w = a[3] * 0.0625f;
  o1.x = a[4] * 0.0625f; o1.y = a[5] * 0.0625f; o1.z = a[6] * 0.0625f; o1.w = a[7] * 0.0625f;
  float* op = out + ((size_t)r << 10) + t * 8;
  *(float4*)op = o0;
  *(float4*)(op + 4) = o1;
}

// ---------------- TN bf16 GEMM core, K unrolled x2 (one barrier pair per 64-K) ----------
// EPI: 0 = bias only, 1 = bias + residual, 2 = bias + GELU (sigmoid approx)
template <int BM, int BN, int WGM, int WGN, int EPI, bool O32, bool O16>
DEVI void gemm_core(const u16* __restrict__ A, int lda,
                    const u16* __restrict__ B, int ldb, int K,
                    const float* __restrict__ bias,
                    const float* __restrict__ resid,
                    float* __restrict__ C32, u16* __restrict__ C16, int ldc,
                    float scale, int m0, int n0) {
  constexpr int WTM = BM / WGM;
  constexpr int WTN = BN / WGN;
  constexpr int FM = WTM / 16;
  constexpr int FN = WTN / 16;
  static_assert(BM % 64 == 0 && BN % 64 == 0, "staging granularity");

  __shared__ __align__(1024) u16 As[2 * BM * 32];   // two BK=32 halves
  __shared__ __align__(1024) u16 Bs[2 * BN * 32];

  const int tid = threadIdx.x;
  const int lane = tid & 63;
  const int wave = tid >> 6;
  const int wr = wave / WGN;
  const int wc = wave % WGN;

  f32x4 acc[FM][FN];
#pragma unroll
  for (int i = 0; i < FM; ++i)
#pragma unroll
    for (int j = 0; j < FN; ++j) acc[i][j] = (f32x4){0.f, 0.f, 0.f, 0.f};

  const int srow = tid >> 2;
  const int sunit = tid & 3;
  const int fr = lane & 15;
  const int c16 = lane >> 4;

  for (int kt = 0; kt < K; kt += 64) {
#pragma unroll
    for (int hh = 0; hh < 2; ++hh) {
      int kb = kt + hh * 32;
#pragma unroll
      for (int ch = 0; ch < BM / 64; ++ch) {
        int r = ch * 64 + srow;
        int gu = sunit ^ ((r >> 1) & 3);
        glds16(A + (size_t)(m0 + r) * lda + kb + gu * 8,
               (char*)As + hh * (BM * 64) + ch * 4096 + tid * 16);
      }
#pragma unroll
      for (int ch = 0; ch < BN / 64; ++ch) {
        int r = ch * 64 + srow;
        int gu = sunit ^ ((r >> 1) & 3);
        glds16(B + (size_t)(n0 + r) * ldb + kb + gu * 8,
               (char*)Bs + hh * (BN * 64) + ch * 4096 + tid * 16);
      }
    }
    __syncthreads();

#pragma unroll
    for (int hh = 0; hh < 2; ++hh) {
      bf16x8 af[FM], bfv[FN];
#pragma unroll
      for (int i = 0; i < FM; ++i) {
        int R = wr * WTM + i * 16 + fr;
        af[i] = *(const bf16x8*)((const char*)As + hh * (BM * 64) + R * 64 +
                                 ((c16 ^ ((R >> 1) & 3)) << 4));
      }
#pragma unroll
      for (int j = 0; j < FN; ++j) {
        int R = wc * WTN + j * 16 + fr;
        bfv[j] = *(const bf16x8*)((const char*)Bs + hh * (BN * 64) + R * 64 +
                                  ((c16 ^ ((R >> 1) & 3)) << 4));
      }
#pragma unroll
      for (int i = 0; i < FM; ++i)
#pragma unroll
        for (int j = 0; j < FN; ++j)
          acc[i][j] = __builtin_amdgcn_mfma_f32_16x16x32_bf16(af[i], bfv[j], acc[i][j], 0, 0, 0);
    }
    __syncthreads();
  }

  const int orow = m0 + wr * WTM + (lane >> 4) * 4;
  const int ocol = n0 + wc * WTN + (lane & 15);
#pragma unroll
  for (int i = 0; i < FM; ++i) {
#pragma unroll
    for (int j = 0; j < FN; ++j) {
      int col = ocol + j * 16;
      float bv = bias ? bias[col] : 0.f;
#pragma unroll
      for (int q = 0; q < 4; ++q) {
        int row = orow + i * 16 + q;
        float v = acc[i][j][q] * scale + bv;
        if (EPI == 2) {
          // gelu(x) ~= x * sigmoid(1.702 x); exp2-based (1.702*log2e = 2.4554669)
          v = v / (1.0f + exp2f(-2.4554669f * v));
        }
        if (EPI == 1) v += resid[(size_t)row * ldc + col];
        if (O32) C32[(size_t)row * ldc + col] = v;
        if (O16) C16[(size_t)row * ldc + col] = f2bf(v);
      }
    }
  }
}

// XCD-chunked swizzle: consecutive logical tiles (x fastest, sharing A panels)
// run on one XCD. Bijective when nwg % 8 == 0 (all our grids satisfy).
template <int BM, int BN, int WGM, int WGN, int EPI, bool O32, bool O16>
__global__ __launch_bounds__(256) void gemm_tn(const u16* __restrict__ A, int lda,
                                               const u16* __restrict__ B, int ldb, int K,
                                               const float* __restrict__ bias,
                                               const float* __restrict__ resid,
                                               float* __restrict__ C32, u16* __restrict__ C16,
                                               int ldc, float scale) {
  u32 gx = gridDim.x;
  u32 nwg = gx * gridDim.y;
  u32 lin = blockIdx.y * gx + blockIdx.x;
  u32 swz = (lin & 7) * (nwg >> 3) + (lin >> 3);
  gemm_core<BM, BN, WGM, WGN, EPI, O32, O16>(A, lda, B, ldb, K, bias, resid, C32, C16, ldc, scale,
                                             (swz / gx) * BM, (swz % gx) * BN);
}

// ff1 (4096x4096, K=1024, GELU): 2D-rect XCD partition over the 32x32 tile grid.
__global__ __launch_bounds__(256) void gemm_ff1(const u16* __restrict__ A,
                                                const u16* __restrict__ B,
                                                const float* __restrict__ bias,
                                                u16* __restrict__ C16) {
  u32 hbid = blockIdx.y * 32 + blockIdx.x;   // 0..1023
  u32 xcd = hbid & 7, idx = hbid >> 3;       // idx 0..127
  u32 rg = xcd >> 2, cg = xcd & 3;           // 2 x 4 XCD rectangle grid
  u32 r = idx >> 3, c = idx & 7;             // 16 rows x 8 cols, x fastest
  gemm_core<128, 128, 2, 2, 2, false, true>(A, 1024, B, 1024, 1024, bias, nullptr, nullptr, C16,
                                            4096, 1.f, (rg * 16 + r) * 128, (cg * 8 + c) * 128);
}

// split-K ff2: K=4096 split in 4; partials f32. XCD swizzle over the full 1024-block grid.
__global__ __launch_bounds__(256) void gemm_splitk_ff2(const u16* __restrict__ A,
                                                       const u16* __restrict__ B,
                                                       float* __restrict__ part) {
  u32 lin = (blockIdx.z * gridDim.y + blockIdx.y) * gridDim.x + blockIdx.x;  // 1024
  u32 swz = (lin & 7) * 128 + (lin >> 3);
  u32 z = swz >> 8, rem = swz & 255;            // 256 tiles per z-slice (32 y x 8 x)
  gemm_core<128, 128, 2, 2, 0, true, false>(A + z * 1024, 4096, B + z * 1024, 4096, 1024, nullptr,
                                            nullptr, part + (size_t)z * 4194304, nullptr, 1024, 1.f,
                                            (rem >> 3) * 128, (rem & 7) * 128);
}

__global__ __launch_bounds__(256) void reduce_ff2(const float* __restrict__ part,
                                                  const float* __restrict__ bias,
                                                  const float* __restrict__ resid,
                                                  float* __restrict__ out) {
  size_t i = ((size_t)blockIdx.x * 256 + threadIdx.x) * 4;
  float4 s0 = *(const float4*)(part + i);
  float4 s1 = *(const float4*)(part + 4194304 + i);
  float4 s2 = *(const float4*)(part + 8388608 + i);
  float4 s3 = *(const float4*)(part + 12582912 + i);
  int col = (int)(i & 1023);
  float4 bv = *(const float4*)(bias + col);
  float4 rv = *(const float4*)(resid + i);
  float4 o;
  o.x = s0.x + s1.x + s2.x + s3.x + bv.x + rv.x;
  o.y = s0.y + s1.y + s2.y + s3.y + bv.y + rv.y;
  o.z = s0.z + s1.z + s2.z + s3.z + bv.z + rv.z;
  o.w = s0.w + s1.w + s2.w + s3.w + bv.w + rv.w;
  *(float4*)(out + i) = o;
}

// ---------------- launch ----------------
extern "C" void kernel_launch(void* const* d_in, const int* in_sizes, int n_in,
                              void* d_out, int out_size, void* d_ws, size_t ws_size,
                              hipStream_t stream) {
  const float* x       = (const float*)d_in[0];
  const float* xa      = (const float*)d_in[1];
  const float* sa_in_w = (const float*)d_in[2];
  const float* sa_in_b = (const float*)d_in[3];
  const float* sa_out_w= (const float*)d_in[4];
  const float* sa_out_b= (const float*)d_in[5];
  const float* ln1_w   = (const float*)d_in[6];
  const float* ln1_b   = (const float*)d_in[7];
  const float* ca_in_w = (const float*)d_in[8];
  const float* ca_in_b = (const float*)d_in[9];
  const float* ca_out_w= (const float*)d_in[10];
  const float* ca_out_b= (const float*)d_in[11];
  const float* ln2_w   = (const float*)d_in[12];
  const float* ln2_b   = (const float*)d_in[13];
  const float* ff_w1   = (const float*)d_in[14];
  const float* ff_b1   = (const float*)d_in[15];
  const float* ff_w2   = (const float*)d_in[16];
  const float* ff_b2   = (const float*)d_in[17];
  const float* ln3_w   = (const float*)d_in[18];
  const float* ln3_b   = (const float*)d_in[19];

  float* out_x     = (float*)d_out;
  float* out_self  = out_x + 4194304;
  float* out_cross = out_x + 8388608;

  char* w = (char*)d_ws;
  u16*   wb_sa_in  = (u16*)(w + 0);
  u16*   wb_sa_out = (u16*)(w + 6291456);
  u16*   wb_ca_in  = (u16*)(w + 8388608);
  u16*   wb_ca_out = (u16*)(w + 14680064);
  u16*   wb_ff1    = (u16*)(w + 16777216);
  u16*   wb_ff2    = (u16*)(w + 25165824);
  float* t32       = (float*)(w + 33554432);
  u16*   t16       = (u16*)(w + 50331648);
  float* x_acc     = (float*)(w + 58720256);
  u16*   qkv       = (u16*)(w + 75497472);
  u16*   vT        = (u16*)(w + 100663296);
  u16*   attnv     = (u16*)(w + 109051904);
  u16*   xa16      = (u16*)(w + 117440512);
  u16*   probs     = (u16*)(w + 125829120);   // 128 MB
  u16*   ff1       = probs;                   // ff1 out reuses first 32 MB
  float* part      = (float*)(w + 159383552); // split-K partials 64 MB

  dim3 blk(256);

  // single batched weight/xa conversion launch
  ConvBatch cb;
  cb.src[0] = sa_in_w;  cb.dst[0] = wb_sa_in;  cb.n[0] = 3145728;
  cb.src[1] = sa_out_w; cb.dst[1] = wb_sa_out; cb.n[1] = 1048576;
  cb.src[2] = ca_in_w;  cb.dst[2] = wb_ca_in;  cb.n[2] = 3145728;
  cb.src[3] = ca_out_w; cb.dst[3] = wb_ca_out; cb.n[3] = 1048576;
  cb.src[4] = ff_w1;    cb.dst[4] = wb_ff1;    cb.n[4] = 4194304;
  cb.src[5] = ff_w2;    cb.dst[5] = wb_ff2;    cb.n[5] = 4194304;
  cb.src[6] = xa;       cb.dst[6] = xa16;      cb.n[6] = 4194304;
  conv_batch<<<dim3(512, 7), blk, 0, stream>>>(cb);

  // ---- self attention ----
  ln_kernel<<<dim3(4096), blk, 0, stream>>>(x, ln1_w, ln1_b, t32, t16);
  gemm_tn<128, 128, 2, 2, 0, false, true><<<dim3(24, 32), blk, 0, stream>>>(
      t16, 1024, wb_sa_in, 1024, 1024, sa_in_b, nullptr, nullptr, qkv, 3072, 1.f);
  transpose_v<<<dim3(16, 64), blk, 0, stream>>>(qkv + 2048, vT);
  attn_fused2<<<dim3(32, 64), blk, 0, stream>>>(qkv, vT, probs, attnv);
  mean_heads<<<dim3(2048), blk, 0, stream>>>(probs, out_self);
  gemm_tn<64, 128, 2, 2, 1, true, false><<<dim3(8, 64), blk, 0, stream>>>(
      attnv, 1024, wb_sa_out, 1024, 1024, sa_out_b, t32, x_acc, nullptr, 1024, 1.f);

  // ---- cross attention ----
  ln_kernel<<<dim3(4096), blk, 0, stream>>>(x_acc, ln2_w, ln2_b, t32, t16);
  gemm_tn<64, 128, 2, 2, 0, false, true><<<dim3(8, 64), blk, 0, stream>>>(
      t16, 1024, wb_ca_in, 1024, 1024, ca_in_b, nullptr, nullptr, qkv, 3072, 1.f);
  gemm_tn<128, 128, 2, 2, 0, false, true><<<dim3(16, 32), blk, 0, stream>>>(
      xa16, 1024, wb_ca_in + 1048576, 1024, 1024, ca_in_b + 1024, nullptr, nullptr, qkv + 1024, 3072, 1.f);
  transpose_v<<<dim3(16, 64), blk, 0, stream>>>(qkv + 2048, vT);
  attn_fused2<<<dim3(32, 64), blk, 0, stream>>>(qkv, vT, probs, attnv);
  mean_heads<<<dim3(2048), blk, 0, stream>>>(probs, out_cross);
  gemm_tn<64, 128, 2, 2, 1, true, false><<<dim3(8, 64), blk, 0, stream>>>(
      attnv, 1024, wb_ca_out, 1024, 1024, ca_out_b, t32, x_acc, nullptr, 1024, 1.f);

  // ---- feed forward ----
  ln_kernel<<<dim3(4096), blk, 0, stream>>>(x_acc, ln3_w, ln3_b, t32, t16);
  gemm_ff1<<<dim3(32, 32), blk, 0, stream>>>(t16, wb_ff1, ff_b1, ff1);
  gemm_splitk_ff2<<<dim3(8, 32, 4), blk, 0, stream>>>(ff1, wb_ff2, part);
  reduce_ff2<<<dim3(4096), blk, 0, stream>>>(part, ff_b2, x_acc, out_x);
}

// Round 24
// 486.759 us; speedup vs baseline: 1.0185x; 1.0185x over previous
//
#include <hip/hip_runtime.h>
#include <cstdint>
#include <cstddef>

// DecoderLayer: B=4, L=S=1024, D=1024, H=16, dh=64, DFF=4096
// Outputs: x [4,1024,1024] f32, self_w [4,1024,1024] f32, cross_w [4,1024,1024] f32
// (revert to round-22 best: 487.6 us; r23's launch_bounds(256,3) cut occupancy 34->28%)

#define DEVI __device__ __forceinline__

typedef unsigned short u16;
typedef unsigned int u32;
typedef float f32x4 __attribute__((ext_vector_type(4)));
typedef short bf16x8 __attribute__((ext_vector_type(8)));

DEVI float bf2f(u16 u) { union { u32 i; float f; } x; x.i = ((u32)u) << 16; return x.f; }
DEVI u16 f2bf(float f) {
  union { float f; u32 i; } x; x.f = f;
  u32 r = x.i + 0x7fffu + ((x.i >> 16) & 1u);
  return (u16)(r >> 16);
}
DEVI u32 cvtpk(float lo, float hi) {  // bf16x2 pack, RTNE
  u32 r;
  asm("v_cvt_pk_bf16_f32 %0, %1, %2" : "=v"(r) : "v"(lo), "v"(hi));
  return r;
}
DEVI float unplo(u32 u) { union { u32 i; float f; } x; x.i = u << 16; return x.f; }
DEVI float unphi(u32 u) { union { u32 i; float f; } x; x.i = u & 0xffff0000u; return x.f; }

typedef const __attribute__((address_space(1))) void GV;
typedef __attribute__((address_space(3))) void LV;
DEVI void glds16(const void* g, void* l) {
  __builtin_amdgcn_global_load_lds((GV*)g, (LV*)l, 16, 0, 0);
}

// ---------------- batched f32 -> bf16 convert (7 tensors, one launch) ----------------
struct ConvBatch {
  const float* src[7];
  u16* dst[7];
  int n[7];
};

__global__ __launch_bounds__(256) void conv_batch(ConvBatch cb) {
  int t = blockIdx.y;
  const float* __restrict__ in = cb.src[t];
  u16* __restrict__ out = cb.dst[t];
  int n = cb.n[t];
  int i = (blockIdx.x * 256 + threadIdx.x) * 4;
  int stride = gridDim.x * 256 * 4;
  for (; i < n; i += stride) {
    float4 v = *(const float4*)(in + i);
    ushort4 o; o.x = f2bf(v.x); o.y = f2bf(v.y); o.z = f2bf(v.z); o.w = f2bf(v.w);
    *(ushort4*)(out + i) = o;
  }
}

// ---------------- LayerNorm over D=1024, writes f32 + bf16 ----------------
__global__ __launch_bounds__(256) void ln_kernel(const float* __restrict__ in,
                                                 const float* __restrict__ gw,
                                                 const float* __restrict__ gb,
                                                 float* __restrict__ o32,
                                                 u16* __restrict__ o16) {
  int row = blockIdx.x;
  int t = threadIdx.x;
  const float* p = in + ((size_t)row << 10);
  float4 v = *(const float4*)(p + t * 4);
  float s = v.x + v.y + v.z + v.w;
  float q = v.x * v.x + v.y * v.y + v.z * v.z + v.w * v.w;
#pragma unroll
  for (int off = 32; off; off >>= 1) { s += __shfl_xor(s, off, 64); q += __shfl_xor(q, off, 64); }
  __shared__ float sb[8];
  int lane = t & 63, wv = t >> 6;
  if (!lane) { sb[wv] = s; sb[4 + wv] = q; }
  __syncthreads();
  s = sb[0] + sb[1] + sb[2] + sb[3];
  q = sb[4] + sb[5] + sb[6] + sb[7];
  float mean = s * (1.f / 1024.f);
  float var = q * (1.f / 1024.f) - mean * mean;
  float rs = rsqrtf(var + 1e-5f);
  float4 w4 = *(const float4*)(gw + t * 4);
  float4 b4 = *(const float4*)(gb + t * 4);
  float y0 = (v.x - mean) * rs * w4.x + b4.x;
  float y1 = (v.y - mean) * rs * w4.y + b4.y;
  float y2 = (v.z - mean) * rs * w4.z + b4.z;
  float y3 = (v.w - mean) * rs * w4.w + b4.w;
  float4 o; o.x = y0; o.y = y1; o.z = y2; o.w = y3;
  *(float4*)(o32 + ((size_t)row << 10) + t * 4) = o;
  ushort4 ob; ob.x = f2bf(y0); ob.y = f2bf(y1); ob.z = f2bf(y2); ob.w = f2bf(y3);
  *(ushort4*)(o16 + ((size_t)row << 10) + t * 4) = ob;
}

// ---------------- transpose V: qkv[(b*1024+s)*3072 + col] -> vT[(bh*64+d)*1024 + s]
__global__ __launch_bounds__(256) void transpose_v(const u16* __restrict__ src, u16* __restrict__ dst) {
  __shared__ u16 tile[64][72];
  int bh = blockIdx.y;
  int b = bh >> 4, h = bh & 15;
  int s0 = blockIdx.x * 64;
  int t = threadIdx.x;
#pragma unroll
  for (int p = 0; p < 4; ++p) {
    int s = p * 16 + (t >> 4);
    int d = (t & 15) * 4;
    ushort4 v = *(const ushort4*)(src + ((size_t)(b * 1024 + s0 + s)) * 3072 + h * 64 + d);
    tile[s][d] = v.x; tile[s][d + 1] = v.y; tile[s][d + 2] = v.z; tile[s][d + 3] = v.w;
  }
  __syncthreads();
#pragma unroll
  for (int p = 0; p < 4; ++p) {
    int d = p * 16 + (t >> 4);
    int s = (t & 15) * 4;
    ushort4 v;
    v.x = tile[s][d]; v.y = tile[s + 1][d]; v.z = tile[s + 2][d]; v.w = tile[s + 3][d];
    *(ushort4*)(dst + ((size_t)(bh * 64 + d)) * 1024 + s0 + s) = v;
  }
}

// ---------------- register-resident fused attention, coalesced P store ----------------
// T5: s_setprio(1) around both MFMA clusters (r22: +1.8us/dispatch).
__global__ __launch_bounds__(256, 4) void attn_fused2(const u16* __restrict__ qkv,
                                                      const u16* __restrict__ vT,
                                                      u16* __restrict__ probs,
                                                      u16* __restrict__ attnv) {
  __shared__ __align__(16) char LdsRaw[32768];  // K halves | P tile [16][1024]u16 | Ored
  __shared__ float wredm[4][2][16];
  __shared__ float wreds[4][2][16];
  float* Ored = (float*)LdsRaw;

  const int hbid = blockIdx.y * 32 + blockIdx.x;          // hw linear id (x fastest)
  const int lbid = (hbid & 7) * 256 + (hbid >> 3);        // XCD-chunked logical id
  const int z = lbid >> 5, b = z >> 4, h = z & 15;
  const int l0 = (lbid & 31) * 32;
  const int tid = threadIdx.x, lane = tid & 63, w = tid >> 6;
  const int fr = lane & 15, c16 = lane >> 4;

  bf16x8 qf[2][2];
#pragma unroll
  for (int i = 0; i < 2; ++i)
#pragma unroll
    for (int kk = 0; kk < 2; ++kk)
      qf[i][kk] = *(const bf16x8*)(qkv + (size_t)(b * 1024 + l0 + 16 * i + fr) * 3072 +
                                   h * 64 + kk * 32 + c16 * 8);

  const u16* Kbase = qkv + (size_t)b * 1024 * 3072 + 1024 + h * 64;

  u32 pk[2][16][2];      // packed bf16 RAW scores (scale folded into exp)
  float mx0 = -1e30f, mx1 = -1e30f;

#pragma unroll
  for (int it = 0; it < 4; ++it) {
    int n = it * 256 + tid;
    int kk = n >> 9, r = (n >> 2) & 127, un = n & 3;
    int su = un ^ ((r >> 1) & 3);
    glds16(Kbase + (size_t)r * 3072 + kk * 32 + su * 8, LdsRaw + n * 16);
  }
  __syncthreads();

#pragma unroll
  for (int cc = 0; cc < 8; ++cc) {
    char* cur = LdsRaw + (cc & 1) * 16384;
    if (cc < 7) {
      char* nxt = LdsRaw + ((cc + 1) & 1) * 16384;
#pragma unroll
      for (int it = 0; it < 4; ++it) {
        int n = it * 256 + tid;
        int kk = n >> 9, r = (n >> 2) & 127, un = n & 3;
        int su = un ^ ((r >> 1) & 3);
        glds16(Kbase + (size_t)((cc + 1) * 128 + r) * 3072 + kk * 32 + su * 8, nxt + n * 16);
      }
    }

    f32x4 acc[2][2];
#pragma unroll
    for (int i = 0; i < 2; ++i)
#pragma unroll
      for (int sj = 0; sj < 2; ++sj) acc[i][sj] = (f32x4){0.f, 0.f, 0.f, 0.f};
    __builtin_amdgcn_s_setprio(1);
#pragma unroll
    for (int kk = 0; kk < 2; ++kk) {
      bf16x8 kf[2];
#pragma unroll
      for (int sj = 0; sj < 2; ++sj) {
        int R = w * 32 + sj * 16 + fr;
        kf[sj] = *(const bf16x8*)(cur + kk * 8192 + R * 64 + ((c16 ^ ((R >> 1) & 3)) << 4));
      }
#pragma unroll
      for (int i = 0; i < 2; ++i)
#pragma unroll
        for (int sj = 0; sj < 2; ++sj)
          acc[i][sj] = __builtin_amdgcn_mfma_f32_16x16x32_bf16(kf[sj], qf[i][kk], acc[i][sj], 0, 0, 0);
    }
    __builtin_amdgcn_s_setprio(0);

    // pack RAW scores, track raw max (scale applied later inside exp)
#pragma unroll
    for (int sj = 0; sj < 2; ++sj) {
      f32x4 a0 = acc[0][sj], a1 = acc[1][sj];
      mx0 = fmaxf(mx0, fmaxf(fmaxf(a0[0], a0[1]), fmaxf(a0[2], a0[3])));
      mx1 = fmaxf(mx1, fmaxf(fmaxf(a1[0], a1[1]), fmaxf(a1[2], a1[3])));
      pk[0][cc * 2 + sj][0] = cvtpk(a0[0], a0[1]); pk[0][cc * 2 + sj][1] = cvtpk(a0[2], a0[3]);
      pk[1][cc * 2 + sj][0] = cvtpk(a1[0], a1[1]); pk[1][cc * 2 + sj][1] = cvtpk(a1[2], a1[3]);
    }
    __syncthreads();
  }

  mx0 = fmaxf(mx0, __shfl_xor(mx0, 16, 64)); mx0 = fmaxf(mx0, __shfl_xor(mx0, 32, 64));
  mx1 = fmaxf(mx1, __shfl_xor(mx1, 16, 64)); mx1 = fmaxf(mx1, __shfl_xor(mx1, 32, 64));
  if (lane < 16) { wredm[w][0][fr] = mx0; wredm[w][1][fr] = mx1; }
  __syncthreads();
  float m0 = fmaxf(fmaxf(wredm[0][0][fr], wredm[1][0][fr]), fmaxf(wredm[2][0][fr], wredm[3][0][fr]));
  float m1 = fmaxf(fmaxf(wredm[0][1][fr], wredm[1][1][fr]), fmaxf(wredm[2][1][fr], wredm[3][1][fr]));

  const float SC = 0.18033688011112042f;   // 0.125 * log2(e)
  float mL0 = m0 * SC, mL1 = m1 * SC;
  float sm0 = 0.f, sm1 = 0.f;
#pragma unroll
  for (int idx = 0; idx < 16; ++idx) {
    u32 a0 = pk[0][idx][0], a1 = pk[0][idx][1];
    float p0 = exp2f(fmaf(unplo(a0), SC, -mL0));
    float p1 = exp2f(fmaf(unphi(a0), SC, -mL0));
    float p2 = exp2f(fmaf(unplo(a1), SC, -mL0));
    float p3 = exp2f(fmaf(unphi(a1), SC, -mL0));
    sm0 += (p0 + p1) + (p2 + p3);
    pk[0][idx][0] = cvtpk(p0, p1); pk[0][idx][1] = cvtpk(p2, p3);
    u32 b0 = pk[1][idx][0], b1 = pk[1][idx][1];
    float q0 = exp2f(fmaf(unplo(b0), SC, -mL1));
    float q1 = exp2f(fmaf(unphi(b0), SC, -mL1));
    float q2 = exp2f(fmaf(unplo(b1), SC, -mL1));
    float q3 = exp2f(fmaf(unphi(b1), SC, -mL1));
    sm1 += (q0 + q1) + (q2 + q3);
    pk[1][idx][0] = cvtpk(q0, q1); pk[1][idx][1] = cvtpk(q2, q3);
  }
  sm0 += __shfl_xor(sm0, 16, 64); sm0 += __shfl_xor(sm0, 32, 64);
  sm1 += __shfl_xor(sm1, 16, 64); sm1 += __shfl_xor(sm1, 32, 64);
  if (lane < 16) { wreds[w][0][fr] = sm0; wreds[w][1][fr] = sm1; }
  __syncthreads();
  float inv0 = 1.f / (wreds[0][0][fr] + wreds[1][0][fr] + wreds[2][0][fr] + wreds[3][0][fr]);
  float inv1 = 1.f / (wreds[0][1][fr] + wreds[1][1][fr] + wreds[2][1][fr] + wreds[3][1][fr]);

#pragma unroll
  for (int i = 0; i < 2; ++i) {
    float inv = i ? inv1 : inv0;
#pragma unroll
    for (int cc = 0; cc < 8; ++cc)
#pragma unroll
      for (int sj = 0; sj < 2; ++sj) {
        int idx = cc * 2 + sj;
        u32 a0 = pk[i][idx][0], a1 = pk[i][idx][1];
        u32 n0 = cvtpk(unplo(a0) * inv, unphi(a0) * inv);
        u32 n1 = cvtpk(unplo(a1) * inv, unphi(a1) * inv);
        pk[i][idx][0] = n0; pk[i][idx][1] = n1;
        int u = cc * 32 + w * 8 + sj * 4 + c16;
        int phys = u ^ (fr & 14);
        uint2 st; st.x = n0; st.y = n1;
        *(uint2*)(LdsRaw + fr * 2048 + phys * 8) = st;
      }
    __syncthreads();
    {
      int r = tid >> 4, pb = tid & 15;
      u16* pg = probs + ((size_t)z << 20) + ((size_t)(l0 + 16 * i + r) << 10);
      int sw = (r & 14) << 3;
#pragma unroll
      for (int j = 0; j < 8; ++j) {
        int p = pb + j * 16;
        bf16x8 v = *(const bf16x8*)(LdsRaw + r * 2048 + ((p * 16) ^ sw));
        *(bf16x8*)(pg + p * 8) = v;
      }
    }
    __syncthreads();
  }

  f32x4 pacc[2][4];
#pragma unroll
  for (int i = 0; i < 2; ++i)
#pragma unroll
    for (int dj = 0; dj < 4; ++dj) pacc[i][dj] = (f32x4){0.f, 0.f, 0.f, 0.f};

  const u16* Vb = vT + ((size_t)z << 16);
  const int laneA = fr + ((c16 & 1) << 5);
  const int laneB = laneA + 16;
  const bool selhi = (c16 & 2) != 0;

#pragma unroll
  for (int cc = 0; cc < 8; ++cc) {
    const int sb = cc * 128 + w * 32;
    const int pidx = cc * 2;
    bf16x8 vf[4];
#pragma unroll
    for (int dj = 0; dj < 4; ++dj)
      vf[dj] = *(const bf16x8*)(Vb + (size_t)(16 * dj + fr) * 1024 + sb + c16 * 8);
#pragma unroll
    for (int i = 0; i < 2; ++i) {
      u32 sA0 = __shfl(pk[i][pidx][0], laneA, 64), sA1 = __shfl(pk[i][pidx][1], laneA, 64);
      u32 sA2 = __shfl(pk[i][pidx + 1][0], laneA, 64), sA3 = __shfl(pk[i][pidx + 1][1], laneA, 64);
      u32 sB0 = __shfl(pk[i][pidx][0], laneB, 64), sB1 = __shfl(pk[i][pidx][1], laneB, 64);
      u32 sB2 = __shfl(pk[i][pidx + 1][0], laneB, 64), sB3 = __shfl(pk[i][pidx + 1][1], laneB, 64);
      union { u32 u[4]; bf16x8 v; } A;
      A.u[0] = selhi ? sA2 : sA0;
      A.u[1] = selhi ? sA3 : sA1;
      A.u[2] = selhi ? sB2 : sB0;
      A.u[3] = selhi ? sB3 : sB1;
      __builtin_amdgcn_s_setprio(1);
#pragma unroll
      for (int dj = 0; dj < 4; ++dj)
        pacc[i][dj] = __builtin_amdgcn_mfma_f32_16x16x32_bf16(A.v, vf[dj], pacc[i][dj], 0, 0, 0);
      __builtin_amdgcn_s_setprio(0);
    }
  }

  if (w < 2) {
    float* Ow = Ored + w * (32 * 68);
#pragma unroll
    for (int i = 0; i < 2; ++i)
#pragma unroll
      for (int dj = 0; dj < 4; ++dj)
#pragma unroll
        for (int q = 0; q < 4; ++q)
          Ow[(16 * i + 4 * c16 + q) * 68 + 16 * dj + fr] = pacc[i][dj][q];
  }
  __syncthreads();
  if (w >= 2) {
    float* Ow = Ored + (w - 2) * (32 * 68);
#pragma unroll
    for (int i = 0; i < 2; ++i)
#pragma unroll
      for (int dj = 0; dj < 4; ++dj)
#pragma unroll
        for (int q = 0; q < 4; ++q)
          Ow[(16 * i + 4 * c16 + q) * 68 + 16 * dj + fr] += pacc[i][dj][q];
  }
  __syncthreads();

  {
    int l = tid >> 3, d0 = (tid & 7) * 8;
    float o[8];
#pragma unroll
    for (int e = 0; e < 8; ++e)
      o[e] = Ored[l * 68 + d0 + e] + Ored[32 * 68 + l * 68 + d0 + e];
    union { u32 u[4]; bf16x8 v; } O;
    O.u[0] = cvtpk(o[0], o[1]); O.u[1] = cvtpk(o[2], o[3]);
    O.u[2] = cvtpk(o[4], o[5]); O.u[3] = cvtpk(o[6], o[7]);
    *(bf16x8*)(attnv + ((size_t)b << 20) + (size_t)(l0 + l) * 1024 + h * 64 + d0) = O.v;
  }
}

// ---------------- mean over 16 heads (16B loads, 2 rows/block) ----------------
__global__ __launch_bounds__(256) void mean_heads(const u16* __restrict__ probs, float* __restrict__ out) {
  int r = blockIdx.x * 2 + (threadIdx.x >> 7);
  int b = r >> 10, l = r & 1023;
  int t = threadIdx.x & 127;
  float a[8];
#pragma unroll
  for (int e = 0; e < 8; ++e) a[e] = 0.f;
  const u16* base = probs + ((size_t)b << 24) + ((size_t)l << 10) + t * 8;
#pragma unroll
  for (int h = 0; h < 16; ++h) {
    bf16x8 v = *(const bf16x8*)(base + ((size_t)h << 20));
#pragma unroll
    for (int e = 0; e < 8; ++e) a[e] += bf2f((u16)v[e]);
  }
  float4 o0, o1;
  o0.x = a[0] * 0.0625f; o0.y = a[1] * 0.0625f; o0.z = a[2] * 0.0625f; o0.w = a[3] * 0.0625f;
  o1.x = a[4] * 0.0625f; o1.y = a[5] * 0.0625f; o1.z = a[6] * 0.0625f; o1.w = a[7] * 0.0625f;
  float* op = out + ((size_t)r << 10) + t * 8;
  *(float4*)op = o0;
  *(float4*)(op + 4) = o1;
}

// ---------------- TN bf16 GEMM core, K unrolled x2 (one barrier pair per 64-K) ----------
// EPI: 0 = bias only, 1 = bias + residual, 2 = bias + GELU (sigmoid approx)
template <int BM, int BN, int WGM, int WGN, int EPI, bool O32, bool O16>
DEVI void gemm_core(const u16* __restrict__ A, int lda,
                    const u16* __restrict__ B, int ldb, int K,
                    const float* __restrict__ bias,
                    const float* __restrict__ resid,
                    float* __restrict__ C32, u16* __restrict__ C16, int ldc,
                    float scale, int m0, int n0) {
  constexpr int WTM = BM / WGM;
  constexpr int WTN = BN / WGN;
  constexpr int FM = WTM / 16;
  constexpr int FN = WTN / 16;
  static_assert(BM % 64 == 0 && BN % 64 == 0, "staging granularity");

  __shared__ __align__(1024) u16 As[2 * BM * 32];   // two BK=32 halves
  __shared__ __align__(1024) u16 Bs[2 * BN * 32];

  const int tid = threadIdx.x;
  const int lane = tid & 63;
  const int wave = tid >> 6;
  const int wr = wave / WGN;
  const int wc = wave % WGN;

  f32x4 acc[FM][FN];
#pragma unroll
  for (int i = 0; i < FM; ++i)
#pragma unroll
    for (int j = 0; j < FN; ++j) acc[i][j] = (f32x4){0.f, 0.f, 0.f, 0.f};

  const int srow = tid >> 2;
  const int sunit = tid & 3;
  const int fr = lane & 15;
  const int c16 = lane >> 4;

  for (int kt = 0; kt < K; kt += 64) {
#pragma unroll
    for (int hh = 0; hh < 2; ++hh) {
      int kb = kt + hh * 32;
#pragma unroll
      for (int ch = 0; ch < BM / 64; ++ch) {
        int r = ch * 64 + srow;
        int gu = sunit ^ ((r >> 1) & 3);
        glds16(A + (size_t)(m0 + r) * lda + kb + gu * 8,
               (char*)As + hh * (BM * 64) + ch * 4096 + tid * 16);
      }
#pragma unroll
      for (int ch = 0; ch < BN / 64; ++ch) {
        int r = ch * 64 + srow;
        int gu = sunit ^ ((r >> 1) & 3);
        glds16(B + (size_t)(n0 + r) * ldb + kb + gu * 8,
               (char*)Bs + hh * (BN * 64) + ch * 4096 + tid * 16);
      }
    }
    __syncthreads();

#pragma unroll
    for (int hh = 0; hh < 2; ++hh) {
      bf16x8 af[FM], bfv[FN];
#pragma unroll
      for (int i = 0; i < FM; ++i) {
        int R = wr * WTM + i * 16 + fr;
        af[i] = *(const bf16x8*)((const char*)As + hh * (BM * 64) + R * 64 +
                                 ((c16 ^ ((R >> 1) & 3)) << 4));
      }
#pragma unroll
      for (int j = 0; j < FN; ++j) {
        int R = wc * WTN + j * 16 + fr;
        bfv[j] = *(const bf16x8*)((const char*)Bs + hh * (BN * 64) + R * 64 +
                                  ((c16 ^ ((R >> 1) & 3)) << 4));
      }
#pragma unroll
      for (int i = 0; i < FM; ++i)
#pragma unroll
        for (int j = 0; j < FN; ++j)
          acc[i][j] = __builtin_amdgcn_mfma_f32_16x16x32_bf16(af[i], bfv[j], acc[i][j], 0, 0, 0);
    }
    __syncthreads();
  }

  const int orow = m0 + wr * WTM + (lane >> 4) * 4;
  const int ocol = n0 + wc * WTN + (lane & 15);
#pragma unroll
  for (int i = 0; i < FM; ++i) {
#pragma unroll
    for (int j = 0; j < FN; ++j) {
      int col = ocol + j * 16;
      float bv = bias ? bias[col] : 0.f;
#pragma unroll
      for (int q = 0; q < 4; ++q) {
        int row = orow + i * 16 + q;
        float v = acc[i][j][q] * scale + bv;
        if (EPI == 2) {
          // gelu(x) ~= x * sigmoid(1.702 x); exp2-based (1.702*log2e = 2.4554669)
          v = v / (1.0f + exp2f(-2.4554669f * v));
        }
        if (EPI == 1) v += resid[(size_t)row * ldc + col];
        if (O32) C32[(size_t)row * ldc + col] = v;
        if (O16) C16[(size_t)row * ldc + col] = f2bf(v);
      }
    }
  }
}

// XCD-chunked swizzle: consecutive logical tiles (x fastest, sharing A panels)
// run on one XCD. Bijective when nwg % 8 == 0 (all our grids satisfy).
template <int BM, int BN, int WGM, int WGN, int EPI, bool O32, bool O16>
__global__ __launch_bounds__(256) void gemm_tn(const u16* __restrict__ A, int lda,
                                               const u16* __restrict__ B, int ldb, int K,
                                               const float* __restrict__ bias,
                                               const float* __restrict__ resid,
                                               float* __restrict__ C32, u16* __restrict__ C16,
                                               int ldc, float scale) {
  u32 gx = gridDim.x;
  u32 nwg = gx * gridDim.y;
  u32 lin = blockIdx.y * gx + blockIdx.x;
  u32 swz = (lin & 7) * (nwg >> 3) + (lin >> 3);
  gemm_core<BM, BN, WGM, WGN, EPI, O32, O16>(A, lda, B, ldb, K, bias, resid, C32, C16, ldc, scale,
                                             (swz / gx) * BM, (swz % gx) * BN);
}

// ff1 (4096x4096, K=1024, GELU): 2D-rect XCD partition over the 32x32 tile grid.
__global__ __launch_bounds__(256) void gemm_ff1(const u16* __restrict__ A,
                                                const u16* __restrict__ B,
                                                const float* __restrict__ bias,
                                                u16* __restrict__ C16) {
  u32 hbid = blockIdx.y * 32 + blockIdx.x;   // 0..1023
  u32 xcd = hbid & 7, idx = hbid >> 3;       // idx 0..127
  u32 rg = xcd >> 2, cg = xcd & 3;           // 2 x 4 XCD rectangle grid
  u32 r = idx >> 3, c = idx & 7;             // 16 rows x 8 cols, x fastest
  gemm_core<128, 128, 2, 2, 2, false, true>(A, 1024, B, 1024, 1024, bias, nullptr, nullptr, C16,
                                            4096, 1.f, (rg * 16 + r) * 128, (cg * 8 + c) * 128);
}

// split-K ff2: K=4096 split in 4; partials f32. XCD swizzle over the full 1024-block grid.
__global__ __launch_bounds__(256) void gemm_splitk_ff2(const u16* __restrict__ A,
                                                       const u16* __restrict__ B,
                                                       float* __restrict__ part) {
  u32 lin = (blockIdx.z * gridDim.y + blockIdx.y) * gridDim.x + blockIdx.x;  // 1024
  u32 swz = (lin & 7) * 128 + (lin >> 3);
  u32 z = swz >> 8, rem = swz & 255;            // 256 tiles per z-slice (32 y x 8 x)
  gemm_core<128, 128, 2, 2, 0, true, false>(A + z * 1024, 4096, B + z * 1024, 4096, 1024, nullptr,
                                            nullptr, part + (size_t)z * 4194304, nullptr, 1024, 1.f,
                                            (rem >> 3) * 128, (rem & 7) * 128);
}

__global__ __launch_bounds__(256) void reduce_ff2(const float* __restrict__ part,
                                                  const float* __restrict__ bias,
                                                  const float* __restrict__ resid,
                                                  float* __restrict__ out) {
  size_t i = ((size_t)blockIdx.x * 256 + threadIdx.x) * 4;
  float4 s0 = *(const float4*)(part + i);
  float4 s1 = *(const float4*)(part + 4194304 + i);
  float4 s2 = *(const float4*)(part + 8388608 + i);
  float4 s3 = *(const float4*)(part + 12582912 + i);
  int col = (int)(i & 1023);
  float4 bv = *(const float4*)(bias + col);
  float4 rv = *(const float4*)(resid + i);
  float4 o;
  o.x = s0.x + s1.x + s2.x + s3.x + bv.x + rv.x;
  o.y = s0.y + s1.y + s2.y + s3.y + bv.y + rv.y;
  o.z = s0.z + s1.z + s2.z + s3.z + bv.z + rv.z;
  o.w = s0.w + s1.w + s2.w + s3.w + bv.w + rv.w;
  *(float4*)(out + i) = o;
}

// ---------------- launch ----------------
extern "C" void kernel_launch(void* const* d_in, const int* in_sizes, int n_in,
                              void* d_out, int out_size, void* d_ws, size_t ws_size,
                              hipStream_t stream) {
  const float* x       = (const float*)d_in[0];
  const float* xa      = (const float*)d_in[1];
  const float* sa_in_w = (const float*)d_in[2];
  const float* sa_in_b = (const float*)d_in[3];
  const float* sa_out_w= (const float*)d_in[4];
  const float* sa_out_b= (const float*)d_in[5];
  const float* ln1_w   = (const float*)d_in[6];
  const float* ln1_b   = (const float*)d_in[7];
  const float* ca_in_w = (const float*)d_in[8];
  const float* ca_in_b = (const float*)d_in[9];
  const float* ca_out_w= (const float*)d_in[10];
  const float* ca_out_b= (const float*)d_in[11];
  const float* ln2_w   = (const float*)d_in[12];
  const float* ln2_b   = (const float*)d_in[13];
  const float* ff_w1   = (const float*)d_in[14];
  const float* ff_b1   = (const float*)d_in[15];
  const float* ff_w2   = (const float*)d_in[16];
  const float* ff_b2   = (const float*)d_in[17];
  const float* ln3_w   = (const float*)d_in[18];
  const float* ln3_b   = (const float*)d_in[19];

  float* out_x     = (float*)d_out;
  float* out_self  = out_x + 4194304;
  float* out_cross = out_x + 8388608;

  char* w = (char*)d_ws;
  u16*   wb_sa_in  = (u16*)(w + 0);
  u16*   wb_sa_out = (u16*)(w + 6291456);
  u16*   wb_ca_in  = (u16*)(w + 8388608);
  u16*   wb_ca_out = (u16*)(w + 14680064);
  u16*   wb_ff1    = (u16*)(w + 16777216);
  u16*   wb_ff2    = (u16*)(w + 25165824);
  float* t32       = (float*)(w + 33554432);
  u16*   t16       = (u16*)(w + 50331648);
  float* x_acc     = (float*)(w + 58720256);
  u16*   qkv       = (u16*)(w + 75497472);
  u16*   vT        = (u16*)(w + 100663296);
  u16*   attnv     = (u16*)(w + 109051904);
  u16*   xa16      = (u16*)(w + 117440512);
  u16*   probs     = (u16*)(w + 125829120);   // 128 MB
  u16*   ff1       = probs;                   // ff1 out reuses first 32 MB
  float* part      = (float*)(w + 159383552); // split-K partials 64 MB

  dim3 blk(256);

  // single batched weight/xa conversion launch
  ConvBatch cb;
  cb.src[0] = sa_in_w;  cb.dst[0] = wb_sa_in;  cb.n[0] = 3145728;
  cb.src[1] = sa_out_w; cb.dst[1] = wb_sa_out; cb.n[1] = 1048576;
  cb.src[2] = ca_in_w;  cb.dst[2] = wb_ca_in;  cb.n[2] = 3145728;
  cb.src[3] = ca_out_w; cb.dst[3] = wb_ca_out; cb.n[3] = 1048576;
  cb.src[4] = ff_w1;    cb.dst[4] = wb_ff1;    cb.n[4] = 4194304;
  cb.src[5] = ff_w2;    cb.dst[5] = wb_ff2;    cb.n[5] = 4194304;
  cb.src[6] = xa;       cb.dst[6] = xa16;      cb.n[6] = 4194304;
  conv_batch<<<dim3(512, 7), blk, 0, stream>>>(cb);

  // ---- self attention ----
  ln_kernel<<<dim3(4096), blk, 0, stream>>>(x, ln1_w, ln1_b, t32, t16);
  gemm_tn<128, 128, 2, 2, 0, false, true><<<dim3(24, 32), blk, 0, stream>>>(
      t16, 1024, wb_sa_in, 1024, 1024, sa_in_b, nullptr, nullptr, qkv, 3072, 1.f);
  transpose_v<<<dim3(16, 64), blk, 0, stream>>>(qkv + 2048, vT);
  attn_fused2<<<dim3(32, 64), blk, 0, stream>>>(qkv, vT, probs, attnv);
  mean_heads<<<dim3(2048), blk, 0, stream>>>(probs, out_self);
  gemm_tn<64, 128, 2, 2, 1, true, false><<<dim3(8, 64), blk, 0, stream>>>(
      attnv, 1024, wb_sa_out, 1024, 1024, sa_out_b, t32, x_acc, nullptr, 1024, 1.f);

  // ---- cross attention ----
  ln_kernel<<<dim3(4096), blk, 0, stream>>>(x_acc, ln2_w, ln2_b, t32, t16);
  gemm_tn<64, 128, 2, 2, 0, false, true><<<dim3(8, 64), blk, 0, stream>>>(
      t16, 1024, wb_ca_in, 1024, 1024, ca_in_b, nullptr, nullptr, qkv, 3072, 1.f);
  gemm_tn<128, 128, 2, 2, 0, false, true><<<dim3(16, 32), blk, 0, stream>>>(
      xa16, 1024, wb_ca_in + 1048576, 1024, 1024, ca_in_b + 1024, nullptr, nullptr, qkv + 1024, 3072, 1.f);
  transpose_v<<<dim3(16, 64), blk, 0, stream>>>(qkv + 2048, vT);
  attn_fused2<<<dim3(32, 64), blk, 0, stream>>>(qkv, vT, probs, attnv);
  mean_heads<<<dim3(2048), blk, 0, stream>>>(probs, out_cross);
  gemm_tn<64, 128, 2, 2, 1, true, false><<<dim3(8, 64), blk, 0, stream>>>(
      attnv, 1024, wb_ca_out, 1024, 1024, ca_out_b, t32, x_acc, nullptr, 1024, 1.f);

  // ---- feed forward ----
  ln_kernel<<<dim3(4096), blk, 0, stream>>>(x_acc, ln3_w, ln3_b, t32, t16);
  gemm_ff1<<<dim3(32, 32), blk, 0, stream>>>(t16, wb_ff1, ff_b1, ff1);
  gemm_splitk_ff2<<<dim3(8, 32, 4), blk, 0, stream>>>(ff1, wb_ff2, part);
  reduce_ff2<<<dim3(4096), blk, 0, stream>>>(part, ff_b2, x_acc, out_x);
}